// Round 1
// baseline (1929.630 us; speedup 1.0000x reference)
//
#include <hip/hip_runtime.h>
#include <cmath>

// Problem constants (fixed by the reference file)
#define B_   8
#define N_   512
#define D_   1024
#define H_   16
#define HD_  64
#define NI_  4
#define BN_  (B_*N_)      // 4096 rows when [B,N,*] is flattened
#define KVLEN (NI_*N_)    // 2048 keys per attention group

// =====================================================================
// Tiled fp32 GEMM: 128x128 tile, BK=8, 256 threads, 8x8 micro-tile.
// A [M,K] row-major (lda=K), W [K,Nc] row-major (ldb=Nc).
// MODE 0: C[M,Nc] = A@W + bias
// MODE 1: transposed store (for IK): ikt[b][c][n] = acc + bias[c]
//         (hardcoded for M=4096 rows = (b,n), Nc=1024)
// MODE 2: C = gate(row) * (A@W) + bias, gate = 1 + (sum of 4 partials)/512
// MODE 3: partial row sums of sigmoid(acc * SCALE/H) -> part[(bz*N_+row)*4+bx]
//         (per-batch GEMM via blockIdx.z; deterministic, no atomics)
// =====================================================================
template<int MODE>
__global__ __launch_bounds__(256) void gemm128(
    const float* __restrict__ A, const float* __restrict__ W,
    const float* __restrict__ bias, float* __restrict__ C,
    int M, int Nc, int K, long sA, long sW,
    const float* __restrict__ part_in, float* __restrict__ part_out)
{
  __shared__ float As[8][132];   // +4 pad: conflict-free transposed writes
  __shared__ float Bs[8][132];
  const int t  = threadIdx.x;
  const int bx = blockIdx.x, by = blockIdx.y, bz = blockIdx.z;
  A += (long)bz * sA;
  W += (long)bz * sW;
  const int rowBase = by * 128, colBase = bx * 128;
  const int arow = t >> 1,  acol = (t & 1) * 4;   // A tile 128x8
  const int brow = t >> 5,  bcol = (t & 31) * 4;  // W tile 8x128
  const int tx = t & 15, ty = t >> 4;

  float acc[8][8] = {};
  const float* Ap = A + (long)(rowBase + arow) * K + acol;
  const float* Wp = W + (long)brow * Nc + colBase + bcol;

  for (int k0 = 0; k0 < K; k0 += 8) {
    float4 av = *(const float4*)(Ap + k0);
    float4 wv = *(const float4*)(Wp + (long)k0 * Nc);
    __syncthreads();
    As[acol+0][arow] = av.x;
    As[acol+1][arow] = av.y;
    As[acol+2][arow] = av.z;
    As[acol+3][arow] = av.w;
    *(float4*)&Bs[brow][bcol] = wv;
    __syncthreads();
    #pragma unroll
    for (int kk = 0; kk < 8; kk++) {
      float a[8], b[8];
      *(float4*)&a[0] = *(const float4*)&As[kk][ty*8];
      *(float4*)&a[4] = *(const float4*)&As[kk][ty*8 + 4];
      *(float4*)&b[0] = *(const float4*)&Bs[kk][tx*4];
      *(float4*)&b[4] = *(const float4*)&Bs[kk][64 + tx*4];
      #pragma unroll
      for (int i = 0; i < 8; i++)
        #pragma unroll
        for (int j = 0; j < 8; j++)
          acc[i][j] = fmaf(a[i], b[j], acc[i][j]);
    }
  }

  const int row = rowBase + ty * 8;
  const int c0 = colBase + tx * 4;
  const int c1 = colBase + 64 + tx * 4;

  if (MODE == 3) {
    const float sc = 0.125f / 16.f;   // SCALE/H
    #pragma unroll
    for (int i = 0; i < 8; i++) {
      float rs = 0.f;
      #pragma unroll
      for (int j = 0; j < 8; j++)
        rs += 1.f / (1.f + __expf(-acc[i][j] * sc));
      // reduce the 128-col segment across the 16 tx-lanes sharing this row
      rs += __shfl_xor(rs, 1);
      rs += __shfl_xor(rs, 2);
      rs += __shfl_xor(rs, 4);
      rs += __shfl_xor(rs, 8);
      if (tx == 0)
        part_out[(long)(bz * N_ + row + i) * 4 + bx] = rs;
    }
    return;
  }

  float4 b0 = *(const float4*)&bias[c0];
  float4 b1 = *(const float4*)&bias[c1];
  #pragma unroll
  for (int i = 0; i < 8; i++) {
    if (MODE == 1) {
      const int bb = (row + i) >> 9;        // batch
      const int nn = (row + i) & (N_ - 1);  // position
      C[((long)bb*D_ + c0 + 0)*N_ + nn] = acc[i][0] + b0.x;
      C[((long)bb*D_ + c0 + 1)*N_ + nn] = acc[i][1] + b0.y;
      C[((long)bb*D_ + c0 + 2)*N_ + nn] = acc[i][2] + b0.z;
      C[((long)bb*D_ + c0 + 3)*N_ + nn] = acc[i][3] + b0.w;
      C[((long)bb*D_ + c1 + 0)*N_ + nn] = acc[i][4] + b1.x;
      C[((long)bb*D_ + c1 + 1)*N_ + nn] = acc[i][5] + b1.y;
      C[((long)bb*D_ + c1 + 2)*N_ + nn] = acc[i][6] + b1.z;
      C[((long)bb*D_ + c1 + 3)*N_ + nn] = acc[i][7] + b1.w;
    } else {
      float g = 1.f;
      if (MODE == 2) {
        const float* p = part_in + (long)(row + i) * 4;
        g = 1.f + (p[0] + p[1] + p[2] + p[3]) * (1.f / 512.f);
      }
      float4 o0, o1;
      o0.x = g*acc[i][0] + b0.x; o0.y = g*acc[i][1] + b0.y;
      o0.z = g*acc[i][2] + b0.z; o0.w = g*acc[i][3] + b0.w;
      o1.x = g*acc[i][4] + b1.x; o1.y = g*acc[i][5] + b1.y;
      o1.z = g*acc[i][6] + b1.z; o1.w = g*acc[i][7] + b1.w;
      *(float4*)&C[(long)(row + i)*Nc + c0] = o0;
      *(float4*)&C[(long)(row + i)*Nc + c1] = o1;
    }
  }
}

// =====================================================================
// Per-head RMSNorm over contiguous 64-element chunks, in place.
// One 64-lane group per (b,n,h); 4 groups per 256-thread block.
// =====================================================================
__global__ __launch_bounds__(256) void rmsnorm64(float* __restrict__ t,
                                                 const float* __restrict__ w)
{
  const int g    = blockIdx.x * 4 + (threadIdx.x >> 6);
  const int lane = threadIdx.x & 63;
  const long base = (long)g * 64;
  float v = t[base + lane];
  float ss = v * v;
  #pragma unroll
  for (int m = 1; m < 64; m <<= 1) ss += __shfl_xor(ss, m);
  const float r = rsqrtf(ss * (1.f / 64.f) + 1e-6f);
  t[base + lane] = v * r * w[lane];
}

// =====================================================================
// Grouped flash attention, fp32.
// grid: (N/64, H, B). 256 threads: 64 queries x 4 dim-groups (16 dims each).
// Each thread keeps its query row's softmax state; the 4 lanes of a query
// reduce the qk dot via shfl_xor. KV tiles of 32 rows staged in LDS.
// q/k/v/out all in [B,N,D] layout; head h = cols h*64..h*64+63.
// =====================================================================
#define TK 32
__global__ __launch_bounds__(256) void attn_fwd(
    const float* __restrict__ q, const float* __restrict__ k,
    const float* __restrict__ v, float* __restrict__ out)
{
  const int b  = blockIdx.z, h = blockIdx.y, qb = blockIdx.x;
  const int t  = threadIdx.x;
  const int ql = t >> 2;          // local query 0..63
  const int dg = t & 3;           // dim group (16 dims)
  const int qi = qb * 64 + ql;    // query index within batch
  const int g  = b >> 2;          // attention group (ni=4)

  __shared__ float Ks[TK][68];    // pad 68: conflict-light
  __shared__ float Vs[TK][68];

  const float* qrow = q + ((long)b * N_ + qi) * D_ + h * HD_ + dg * 16;
  float qreg[16];
  *(float4*)&qreg[0]  = *(const float4*)&qrow[0];
  *(float4*)&qreg[4]  = *(const float4*)&qrow[4];
  *(float4*)&qreg[8]  = *(const float4*)&qrow[8];
  *(float4*)&qreg[12] = *(const float4*)&qrow[12];

  float m = -1e30f, l = 0.f;
  float o[16];
  #pragma unroll
  for (int j = 0; j < 16; j++) o[j] = 0.f;

  const int lr = t >> 3;          // tile-load row 0..31
  const int lc = (t & 7) * 8;     // tile-load col base

  for (int kt = 0; kt < KVLEN / TK; ++kt) {
    const int mi   = kt * TK + lr;
    const int inst = mi >> 9;           // which instance in the group
    const int nn   = mi & (N_ - 1);
    const long src = ((long)(g * NI_ + inst) * N_ + nn) * D_ + h * HD_ + lc;
    __syncthreads();   // previous tile fully consumed
    *(float4*)&Ks[lr][lc]     = *(const float4*)&k[src];
    *(float4*)&Ks[lr][lc + 4] = *(const float4*)&k[src + 4];
    *(float4*)&Vs[lr][lc]     = *(const float4*)&v[src];
    *(float4*)&Vs[lr][lc + 4] = *(const float4*)&v[src + 4];
    __syncthreads();

    float sv[TK];
    float smax = m;
    #pragma unroll
    for (int kk = 0; kk < TK; kk++) {
      float s = 0.f;
      #pragma unroll
      for (int j = 0; j < 16; j++)
        s = fmaf(qreg[j], Ks[kk][dg * 16 + j], s);
      s += __shfl_xor(s, 1);   // reduce the 4 lanes of this query
      s += __shfl_xor(s, 2);
      s *= 0.125f;             // SCALE
      sv[kk] = s;
      smax = fmaxf(smax, s);
    }
    const float scale = __expf(m - smax);
    l *= scale;
    #pragma unroll
    for (int j = 0; j < 16; j++) o[j] *= scale;
    #pragma unroll
    for (int kk = 0; kk < TK; kk++) {
      const float p = __expf(sv[kk] - smax);
      l += p;
      #pragma unroll
      for (int j = 0; j < 16; j++)
        o[j] = fmaf(p, Vs[kk][dg * 16 + j], o[j]);
    }
    m = smax;
  }

  const float inv = 1.f / l;
  float* orow = out + ((long)b * N_ + qi) * D_ + h * HD_ + dg * 16;
  float4 r0, r1, r2, r3;
  r0.x=o[0]*inv;  r0.y=o[1]*inv;  r0.z=o[2]*inv;  r0.w=o[3]*inv;
  r1.x=o[4]*inv;  r1.y=o[5]*inv;  r1.z=o[6]*inv;  r1.w=o[7]*inv;
  r2.x=o[8]*inv;  r2.y=o[9]*inv;  r2.z=o[10]*inv; r2.w=o[11]*inv;
  r3.x=o[12]*inv; r3.y=o[13]*inv; r3.z=o[14]*inv; r3.w=o[15]*inv;
  *(float4*)&orow[0]  = r0;
  *(float4*)&orow[4]  = r1;
  *(float4*)&orow[8]  = r2;
  *(float4*)&orow[12] = r3;
}

// =====================================================================
// inst_feat[b,n,:] = instance_mask[b,n,0..3] @ instance_embed[0,0..3,:]
// One thread per 4 output elements.
// =====================================================================
__global__ __launch_bounds__(256) void instfeat(
    const float* __restrict__ mask, const float* __restrict__ emb,
    float* __restrict__ outf)
{
  const long idx = (long)blockIdx.x * 256 + threadIdx.x;  // BN_*D_/4 total
  const int  d4  = (int)(idx & (D_ / 4 - 1));
  const long bn  = idx >> 8;
  const float* mk = mask + bn * NI_;
  float4 acc = {0.f, 0.f, 0.f, 0.f};
  #pragma unroll
  for (int i = 0; i < NI_; i++) {
    const float mm = mk[i];
    const float4 e = *(const float4*)&emb[(long)i * D_ + d4 * 4];
    acc.x = fmaf(mm, e.x, acc.x);
    acc.y = fmaf(mm, e.y, acc.y);
    acc.z = fmaf(mm, e.z, acc.z);
    acc.w = fmaf(mm, e.w, acc.w);
  }
  *(float4*)&outf[bn * D_ + d4 * 4] = acc;
}

// =====================================================================
extern "C" void kernel_launch(void* const* d_in, const int* in_sizes, int n_in,
                              void* d_out, int out_size, void* d_ws, size_t ws_size,
                              hipStream_t stream)
{
  const float* x    = (const float*)d_in[0];
  const float* mask = (const float*)d_in[1];
  const float* Wq   = (const float*)d_in[2];
  const float* bq   = (const float*)d_in[3];
  const float* Wk   = (const float*)d_in[4];
  const float* bk   = (const float*)d_in[5];
  const float* Wv   = (const float*)d_in[6];
  const float* bv   = (const float*)d_in[7];
  const float* Wo   = (const float*)d_in[8];
  const float* bo   = (const float*)d_in[9];
  const float* Wiq  = (const float*)d_in[10];
  const float* biq  = (const float*)d_in[11];
  const float* Wik  = (const float*)d_in[12];
  const float* bik  = (const float*)d_in[13];
  const float* emb  = (const float*)d_in[14];
  const float* qnw  = (const float*)d_in[15];
  const float* knw  = (const float*)d_in[16];
  float* out = (float*)d_out;

  // Workspace carve-up (floats). Buffers are reused once their producer's
  // consumers are done: q->iq, k->inst_feat, v->ik^T. Total ~67.2 MB.
  float* ws   = (float*)d_ws;
  const size_t SZ = (size_t)BN_ * D_;   // 4.19M floats
  float* qbuf = ws;
  float* kbuf = qbuf + SZ;
  float* vbuf = kbuf + SZ;
  float* obuf = vbuf + SZ;
  float* part = obuf + SZ;              // [B*N, 4] gate partial sums
  float* iq   = qbuf;                   // alias after attention
  float* ifeat= kbuf;
  float* ikt  = vbuf;                   // [B][D][N] transposed IK

  const dim3 blk(256);
  const dim3 gProj(D_ / 128, BN_ / 128, 1);     // 8 x 32

  // 1) QKV projections
  gemm128<0><<<gProj, blk, 0, stream>>>(x, Wq, bq, qbuf, BN_, D_, D_, 0, 0, nullptr, nullptr);
  gemm128<0><<<gProj, blk, 0, stream>>>(x, Wk, bk, kbuf, BN_, D_, D_, 0, 0, nullptr, nullptr);
  gemm128<0><<<gProj, blk, 0, stream>>>(x, Wv, bv, vbuf, BN_, D_, D_, 0, 0, nullptr, nullptr);

  // 2) QK RMSNorm (per-head, 64-elem chunks)
  rmsnorm64<<<BN_ * H_ / 4, blk, 0, stream>>>(qbuf, qnw);
  rmsnorm64<<<BN_ * H_ / 4, blk, 0, stream>>>(kbuf, knw);

  // 3) Grouped attention -> obuf [B,N,D]
  attn_fwd<<<dim3(N_ / 64, H_, B_), blk, 0, stream>>>(qbuf, kbuf, vbuf, obuf);

  // 4) IQ = out@Wiq+biq (overwrites qbuf)
  gemm128<0><<<gProj, blk, 0, stream>>>(obuf, Wiq, biq, iq, BN_, D_, D_, 0, 0, nullptr, nullptr);

  // 5) inst_feat (overwrites kbuf)
  instfeat<<<(BN_ * D_ / 4) / 256, blk, 0, stream>>>(mask, emb, ifeat);

  // 6) IK^T = (inst_feat@Wik+bik)^T per batch (overwrites vbuf)
  gemm128<1><<<gProj, blk, 0, stream>>>(ifeat, Wik, bik, ikt, BN_, D_, D_, 0, 0, nullptr, nullptr);

  // 7) gate partials: per-batch IQ[b] @ IKT[b], sigmoid, row-sum partials
  gemm128<3><<<dim3(N_ / 128, N_ / 128, B_), blk, 0, stream>>>(
      iq, ikt, nullptr, nullptr, N_, N_, D_,
      (long)N_ * D_, (long)D_ * N_, nullptr, part);

  // 8) final: (out * gate) @ Wo + bo -> d_out (gate folded into epilogue)
  gemm128<2><<<gProj, blk, 0, stream>>>(obuf, Wo, bo, out, BN_, D_, D_, 0, 0, part, nullptr);
}

// Round 4
// 1257.202 us; speedup vs baseline: 1.5349x; 1.5349x over previous
//
#include <hip/hip_runtime.h>
#include <cmath>

// Problem constants (fixed by the reference file)
#define B_   8
#define N_   512
#define D_   1024
#define H_   16
#define HD_  64
#define NI_  4
#define BN_  (B_*N_)      // 4096 rows when [B,N,*] is flattened
#define KVLEN (NI_*N_)    // 2048 keys per attention group

typedef __attribute__((ext_vector_type(8)))  short  bf16x8;   // 8 bf16 bit patterns
typedef __attribute__((ext_vector_type(8)))  __bf16 bf16x8_t; // builtin operand type
typedef __attribute__((ext_vector_type(16))) float  f32x16;
typedef __attribute__((ext_vector_type(4)))  short  s16x4;

// round-to-nearest-even bf16 conversion (bit trick)
__device__ __forceinline__ short bf16_rn(float x) {
  unsigned u = __float_as_uint(x);
  unsigned r = (u + 0x7FFFu + ((u >> 16) & 1u)) >> 16;
  return (short)r;
}

// RN hi/lo split: x = hi + lo + eps, |eps| <~ 2^-18 |x|.
__device__ __forceinline__ void split2(float x, short& hi, short& lo) {
  hi = bf16_rn(x);
  float h = __uint_as_float(((unsigned)(unsigned short)hi) << 16);
  float r = x - h;              // exact (Dekker-style split)
  lo = bf16_rn(r);
}

__device__ __forceinline__ f32x16 mfma_bf16(bf16x8 a, bf16x8 b, f32x16 c) {
  return __builtin_amdgcn_mfma_f32_32x32x16_bf16(
      __builtin_bit_cast(bf16x8_t, a), __builtin_bit_cast(bf16x8_t, b), c, 0, 0, 0);
}

// =====================================================================
// Weight transpose + hi/lo split: W[K=1024][C=1024] fp32 ->
// Thi/Tlo[C][K] bf16.  64x64 tiles via LDS.
// =====================================================================
__global__ __launch_bounds__(256) void wsplitT(const float* __restrict__ W,
                                               short* __restrict__ Thi,
                                               short* __restrict__ Tlo)
{
  __shared__ float tile[64][65];
  const int t  = threadIdx.x;
  const int kb = blockIdx.y * 64;   // source row block (k)
  const int cb = blockIdx.x * 64;   // source col block
  const int r0 = t >> 4;            // 0..15
  const int c4 = t & 15;            // float4 index within row
  #pragma unroll
  for (int i = 0; i < 4; i++) {
    const int r = r0 + i * 16;
    *(float4*)&tile[r][c4 * 4] = *(const float4*)&W[(long)(kb + r) * D_ + cb + c4 * 4];
  }
  __syncthreads();
  #pragma unroll
  for (int i = 0; i < 4; i++) {
    const int c = r0 + i * 16;      // source col = output row
    short hi[4], lo[4];
    #pragma unroll
    for (int e = 0; e < 4; e++)
      split2(tile[c4 * 4 + e][c], hi[e], lo[e]);
    *(s16x4*)&Thi[(long)(cb + c) * D_ + kb + c4 * 4] = *(s16x4*)hi;
    *(s16x4*)&Tlo[(long)(cb + c) * D_ + kb + c4 * 4] = *(s16x4*)lo;
  }
}

// =====================================================================
// Split-bf16 MFMA GEMM.  BM=BN=128, BK=32, 256 threads = 4 waves (2x2),
// per-wave 64x64 output as 2x2 frags of v_mfma_f32_32x32x16_bf16.
// A: fp32 [M,K] (+bz*sA), converted to hi/lo bf16 during staging.
// B: PRE-SPLIT bf16, [col][k] row-major (+bz*sB).
// 3 MFMAs per operand pair: Al*Bh + Ah*Bl + Ah*Bh (fp32-like accuracy).
// MODE 0: C = A@B + bias (fp32 out)
// MODE 1: split output: Chi/Clo bf16 = A@B + bias  (for ik)
// MODE 2: C = gate(row)*(A@B) + bias, gate = 1 + sum8(part_in[row])/512
// MODE 3: part_out[(bz*N_+row)*8 + bx*2 + wc] = this wave's 64-col partial
//         row sum of sigmoid(acc*SCALE/H).
//         (Round-3 lesson: waves (wr,0) and (wr,1) cover the SAME rows;
//          a shared [row*4+bx] slot was a write-write race that dropped
//          exactly half the sigmoid mass -> output scaled by 5/6 -> the
//          bit-exact 0.169921875/6 failure. One slot per wave fixes it.)
// =====================================================================
#define BM 128
#define BN 128
#define BK 32
#define PAD 40   // LDS row stride in shorts (bank-spread padding)

template<int MODE>
__global__ __launch_bounds__(256) void mfgemm(
    const float* __restrict__ A, const short* __restrict__ Bhi,
    const short* __restrict__ Blo, const float* __restrict__ bias,
    float* __restrict__ C, short* __restrict__ Chi, short* __restrict__ Clo,
    int M, int Nc, int K, long sA, long sB,
    const float* __restrict__ part_in, float* __restrict__ part_out)
{
  __shared__ short As[2][BM][PAD];   // [hi/lo][row][k]
  __shared__ short Bs[2][BN][PAD];   // [hi/lo][col][k]
  const int t  = threadIdx.x;
  const int bx = blockIdx.x, by = blockIdx.y, bz = blockIdx.z;
  A   += (long)bz * sA;
  Bhi += (long)bz * sB;
  Blo += (long)bz * sB;
  const int rowBase = by * BM, colBase = bx * BN;

  // staging maps
  const int sa_row = t >> 3;        // + 32*i
  const int sa_c4  = t & 7;         // float4 index in the 32-wide k tile
  const int sb_col = t >> 2;        // + 64*(i&1)
  const int sb_q   = t & 3;         // 8-short chunk index

  float4 aReg[4];
  int4   bReg[4];

  auto loadTile = [&](int k0) {
    #pragma unroll
    for (int i = 0; i < 4; i++)
      aReg[i] = *(const float4*)&A[(long)(rowBase + sa_row + 32 * i) * K + k0 + sa_c4 * 4];
    #pragma unroll
    for (int i = 0; i < 4; i++) {
      const short* p = (i >> 1) ? Blo : Bhi;
      bReg[i] = *(const int4*)&p[(long)(colBase + (i & 1) * 64 + sb_col) * K + k0 + sb_q * 8];
    }
  };
  auto writeTile = [&]() {
    #pragma unroll
    for (int i = 0; i < 4; i++) {
      short hi[4], lo[4];
      split2(aReg[i].x, hi[0], lo[0]);
      split2(aReg[i].y, hi[1], lo[1]);
      split2(aReg[i].z, hi[2], lo[2]);
      split2(aReg[i].w, hi[3], lo[3]);
      *(s16x4*)&As[0][sa_row + 32 * i][sa_c4 * 4] = *(s16x4*)hi;
      *(s16x4*)&As[1][sa_row + 32 * i][sa_c4 * 4] = *(s16x4*)lo;
    }
    #pragma unroll
    for (int i = 0; i < 4; i++)
      *(int4*)&Bs[i >> 1][(i & 1) * 64 + sb_col][sb_q * 8] = bReg[i];
  };

  const int w = t >> 6, lane = t & 63;
  const int wr = w >> 1, wc = w & 1;
  const int lrow = lane & 31, lk = lane >> 5;

  f32x16 acc[2][2] = {};

  auto compute = [&]() {
    #pragma unroll
    for (int kh = 0; kh < 2; kh++) {
      const int ko = kh * 16 + lk * 8;
      bf16x8 ah[2], al[2], bh[2], bl[2];
      #pragma unroll
      for (int m = 0; m < 2; m++) {
        ah[m] = *(const bf16x8*)&As[0][wr * 64 + m * 32 + lrow][ko];
        al[m] = *(const bf16x8*)&As[1][wr * 64 + m * 32 + lrow][ko];
      }
      #pragma unroll
      for (int n = 0; n < 2; n++) {
        bh[n] = *(const bf16x8*)&Bs[0][wc * 64 + n * 32 + lrow][ko];
        bl[n] = *(const bf16x8*)&Bs[1][wc * 64 + n * 32 + lrow][ko];
      }
      #pragma unroll
      for (int m = 0; m < 2; m++)
        #pragma unroll
        for (int n = 0; n < 2; n++) {
          acc[m][n] = mfma_bf16(al[m], bh[n], acc[m][n]);
          acc[m][n] = mfma_bf16(ah[m], bl[n], acc[m][n]);
          acc[m][n] = mfma_bf16(ah[m], bh[n], acc[m][n]);
        }
    }
  };

  const int NT = K / BK;
  loadTile(0);
  writeTile();
  __syncthreads();
  for (int tt = 0; tt < NT; ++tt) {
    if (tt + 1 < NT) loadTile((tt + 1) * BK);
    compute();
    __syncthreads();
    if (tt + 1 < NT) { writeTile(); __syncthreads(); }
  }

  // ---------------- epilogue ----------------
  if (MODE == 3) {
    const float sc = 0.125f / 16.f;   // SCALE/H
    #pragma unroll
    for (int m = 0; m < 2; m++)
      #pragma unroll
      for (int r = 0; r < 16; r++) {
        const int row = rowBase + wr * 64 + m * 32 + (r & 3) + 8 * (r >> 2) + 4 * lk;
        float v = 1.f / (1.f + __expf(-acc[m][0][r] * sc))
                + 1.f / (1.f + __expf(-acc[m][1][r] * sc));
        v += __shfl_xor(v, 1);  v += __shfl_xor(v, 2);  v += __shfl_xor(v, 4);
        v += __shfl_xor(v, 8);  v += __shfl_xor(v, 16);
        if (lrow == 0)
          part_out[(long)(bz * N_ + row) * 8 + bx * 2 + wc] = v;
      }
    return;
  }

  float bcol[2];
  #pragma unroll
  for (int n = 0; n < 2; n++)
    bcol[n] = bias[colBase + wc * 64 + n * 32 + lrow];

  #pragma unroll
  for (int m = 0; m < 2; m++) {
    #pragma unroll
    for (int r = 0; r < 16; r++) {
      const int row = rowBase + wr * 64 + m * 32 + (r & 3) + 8 * (r >> 2) + 4 * lk;
      float g = 1.f;
      if (MODE == 2) {
        const float4 p0 = *(const float4*)&part_in[(long)row * 8];
        const float4 p1 = *(const float4*)&part_in[(long)row * 8 + 4];
        g = 1.f + (p0.x + p0.y + p0.z + p0.w + p1.x + p1.y + p1.z + p1.w)
                  * (1.f / 512.f);
      }
      #pragma unroll
      for (int n = 0; n < 2; n++) {
        const int col = colBase + wc * 64 + n * 32 + lrow;
        const float val = acc[m][n][r] * g + bcol[n];
        if (MODE == 1) {
          short hi, lo;
          split2(val, hi, lo);
          Chi[(long)row * Nc + col] = hi;
          Clo[(long)row * Nc + col] = lo;
        } else {
          C[(long)row * Nc + col] = val;
        }
      }
    }
  }
}

// =====================================================================
// Per-head RMSNorm over contiguous 64-element chunks, in place.
// =====================================================================
__global__ __launch_bounds__(256) void rmsnorm64(float* __restrict__ t,
                                                 const float* __restrict__ w)
{
  const int g    = blockIdx.x * 4 + (threadIdx.x >> 6);
  const int lane = threadIdx.x & 63;
  const long base = (long)g * 64;
  float v = t[base + lane];
  float ss = v * v;
  #pragma unroll
  for (int m = 1; m < 64; m <<= 1) ss += __shfl_xor(ss, m);
  const float r = rsqrtf(ss * (1.f / 64.f) + 1e-6f);
  t[base + lane] = v * r * w[lane];
}

// =====================================================================
// Grouped flash attention, fp32 (unchanged this round).
// =====================================================================
#define TK 32
__global__ __launch_bounds__(256) void attn_fwd(
    const float* __restrict__ q, const float* __restrict__ k,
    const float* __restrict__ v, float* __restrict__ out)
{
  const int b  = blockIdx.z, h = blockIdx.y, qb = blockIdx.x;
  const int t  = threadIdx.x;
  const int ql = t >> 2;          // local query 0..63
  const int dg = t & 3;           // dim group (16 dims)
  const int qi = qb * 64 + ql;
  const int g  = b >> 2;

  __shared__ float Ks[TK][68];
  __shared__ float Vs[TK][68];

  const float* qrow = q + ((long)b * N_ + qi) * D_ + h * HD_ + dg * 16;
  float qreg[16];
  *(float4*)&qreg[0]  = *(const float4*)&qrow[0];
  *(float4*)&qreg[4]  = *(const float4*)&qrow[4];
  *(float4*)&qreg[8]  = *(const float4*)&qrow[8];
  *(float4*)&qreg[12] = *(const float4*)&qrow[12];

  float m = -1e30f, l = 0.f;
  float o[16];
  #pragma unroll
  for (int j = 0; j < 16; j++) o[j] = 0.f;

  const int lr = t >> 3;
  const int lc = (t & 7) * 8;

  for (int kt = 0; kt < KVLEN / TK; ++kt) {
    const int mi   = kt * TK + lr;
    const int inst = mi >> 9;
    const int nn   = mi & (N_ - 1);
    const long src = ((long)(g * NI_ + inst) * N_ + nn) * D_ + h * HD_ + lc;
    __syncthreads();
    *(float4*)&Ks[lr][lc]     = *(const float4*)&k[src];
    *(float4*)&Ks[lr][lc + 4] = *(const float4*)&k[src + 4];
    *(float4*)&Vs[lr][lc]     = *(const float4*)&v[src];
    *(float4*)&Vs[lr][lc + 4] = *(const float4*)&v[src + 4];
    __syncthreads();

    float sv[TK];
    float smax = m;
    #pragma unroll
    for (int kk = 0; kk < TK; kk++) {
      float s = 0.f;
      #pragma unroll
      for (int j = 0; j < 16; j++)
        s = fmaf(qreg[j], Ks[kk][dg * 16 + j], s);
      s += __shfl_xor(s, 1);
      s += __shfl_xor(s, 2);
      s *= 0.125f;
      sv[kk] = s;
      smax = fmaxf(smax, s);
    }
    const float scale = __expf(m - smax);
    l *= scale;
    #pragma unroll
    for (int j = 0; j < 16; j++) o[j] *= scale;
    #pragma unroll
    for (int kk = 0; kk < TK; kk++) {
      const float p = __expf(sv[kk] - smax);
      l += p;
      #pragma unroll
      for (int j = 0; j < 16; j++)
        o[j] = fmaf(p, Vs[kk][dg * 16 + j], o[j]);
    }
    m = smax;
  }

  const float inv = 1.f / l;
  float* orow = out + ((long)b * N_ + qi) * D_ + h * HD_ + dg * 16;
  float4 r0, r1, r2, r3;
  r0.x=o[0]*inv;  r0.y=o[1]*inv;  r0.z=o[2]*inv;  r0.w=o[3]*inv;
  r1.x=o[4]*inv;  r1.y=o[5]*inv;  r1.z=o[6]*inv;  r1.w=o[7]*inv;
  r2.x=o[8]*inv;  r2.y=o[9]*inv;  r2.z=o[10]*inv; r2.w=o[11]*inv;
  r3.x=o[12]*inv; r3.y=o[13]*inv; r3.z=o[14]*inv; r3.w=o[15]*inv;
  *(float4*)&orow[0]  = r0;
  *(float4*)&orow[4]  = r1;
  *(float4*)&orow[8]  = r2;
  *(float4*)&orow[12] = r3;
}

// =====================================================================
// inst_feat[b,n,:] = instance_mask[b,n,0..3] @ instance_embed[0,0..3,:]
// =====================================================================
__global__ __launch_bounds__(256) void instfeat(
    const float* __restrict__ mask, const float* __restrict__ emb,
    float* __restrict__ outf)
{
  const long idx = (long)blockIdx.x * 256 + threadIdx.x;
  const int  d4  = (int)(idx & (D_ / 4 - 1));
  const long bn  = idx >> 8;
  const float* mk = mask + bn * NI_;
  float4 acc = {0.f, 0.f, 0.f, 0.f};
  #pragma unroll
  for (int i = 0; i < NI_; i++) {
    const float mm = mk[i];
    const float4 e = *(const float4*)&emb[(long)i * D_ + d4 * 4];
    acc.x = fmaf(mm, e.x, acc.x);
    acc.y = fmaf(mm, e.y, acc.y);
    acc.z = fmaf(mm, e.z, acc.z);
    acc.w = fmaf(mm, e.w, acc.w);
  }
  *(float4*)&outf[bn * D_ + d4 * 4] = acc;
}

// =====================================================================
extern "C" void kernel_launch(void* const* d_in, const int* in_sizes, int n_in,
                              void* d_out, int out_size, void* d_ws, size_t ws_size,
                              hipStream_t stream)
{
  const float* x    = (const float*)d_in[0];
  const float* mask = (const float*)d_in[1];
  const float* Wq   = (const float*)d_in[2];
  const float* bq   = (const float*)d_in[3];
  const float* Wk   = (const float*)d_in[4];
  const float* bk   = (const float*)d_in[5];
  const float* Wv   = (const float*)d_in[6];
  const float* bv   = (const float*)d_in[7];
  const float* Wo   = (const float*)d_in[8];
  const float* bo   = (const float*)d_in[9];
  const float* Wiq  = (const float*)d_in[10];
  const float* biq  = (const float*)d_in[11];
  const float* Wik  = (const float*)d_in[12];
  const float* bik  = (const float*)d_in[13];
  const float* emb  = (const float*)d_in[14];
  const float* qnw  = (const float*)d_in[15];
  const float* knw  = (const float*)d_in[16];
  float* out = (float*)d_out;

  // Workspace (~68.2 MB): 4 fp32 [4096,1024] buffers + part[BN,8] + one
  // transposed-weight hi/lo slot (reused for all 6 weights, stream-serial).
  float* ws   = (float*)d_ws;
  const size_t SZ = (size_t)BN_ * D_;
  float* qbuf = ws;
  float* kbuf = qbuf + SZ;
  float* vbuf = kbuf + SZ;
  float* obuf = vbuf + SZ;
  float* part = obuf + SZ;              // [B*N, 8] per-wave gate partials
  short* Whi  = (short*)(part + (size_t)BN_ * 8);
  short* Wlo  = Whi + (size_t)D_ * D_;
  float* iq    = qbuf;                  // aliases (post-attention)
  float* ifeat = kbuf;
  short* ikh   = (short*)vbuf;
  short* ikl   = ikh + SZ;

  const dim3 blk(256);
  const dim3 gT(D_ / 64, D_ / 64, 1);           // weight transpose grid
  const dim3 gProj(D_ / BN, BN_ / BM, 1);       // 8 x 32
  const dim3 gGate(N_ / BN, N_ / BM, B_);       // 4 x 4 x 8

  // 1) QKV projections (transpose+split each weight, then GEMM)
  wsplitT<<<gT, blk, 0, stream>>>(Wq, Whi, Wlo);
  mfgemm<0><<<gProj, blk, 0, stream>>>(x, Whi, Wlo, bq, qbuf, nullptr, nullptr,
                                       BN_, D_, D_, 0, 0, nullptr, nullptr);
  wsplitT<<<gT, blk, 0, stream>>>(Wk, Whi, Wlo);
  mfgemm<0><<<gProj, blk, 0, stream>>>(x, Whi, Wlo, bk, kbuf, nullptr, nullptr,
                                       BN_, D_, D_, 0, 0, nullptr, nullptr);
  wsplitT<<<gT, blk, 0, stream>>>(Wv, Whi, Wlo);
  mfgemm<0><<<gProj, blk, 0, stream>>>(x, Whi, Wlo, bv, vbuf, nullptr, nullptr,
                                       BN_, D_, D_, 0, 0, nullptr, nullptr);

  // 2) QK RMSNorm
  rmsnorm64<<<BN_ * H_ / 4, blk, 0, stream>>>(qbuf, qnw);
  rmsnorm64<<<BN_ * H_ / 4, blk, 0, stream>>>(kbuf, knw);

  // 3) Grouped attention -> obuf
  attn_fwd<<<dim3(N_ / 64, H_, B_), blk, 0, stream>>>(qbuf, kbuf, vbuf, obuf);

  // 4) IQ = obuf@Wiq+biq (overwrites qbuf)
  wsplitT<<<gT, blk, 0, stream>>>(Wiq, Whi, Wlo);
  mfgemm<0><<<gProj, blk, 0, stream>>>(obuf, Whi, Wlo, biq, iq, nullptr, nullptr,
                                       BN_, D_, D_, 0, 0, nullptr, nullptr);

  // 5) inst_feat (overwrites kbuf)
  instfeat<<<(BN_ * D_ / 4) / 256, blk, 0, stream>>>(mask, emb, ifeat);

  // 6) IK = inst_feat@Wik+bik, emitted as split bf16 [B*N][D] (overwrites vbuf)
  wsplitT<<<gT, blk, 0, stream>>>(Wik, Whi, Wlo);
  mfgemm<1><<<gProj, blk, 0, stream>>>(ifeat, Whi, Wlo, bik, nullptr, ikh, ikl,
                                       BN_, D_, D_, 0, 0, nullptr, nullptr);

  // 7) gate partials: per-batch IQ[b] @ IK[b]^T, sigmoid, per-wave partial sums
  mfgemm<3><<<gGate, blk, 0, stream>>>(iq, ikh, ikl, nullptr, nullptr, nullptr, nullptr,
                                       N_, N_, D_, (long)N_ * D_, (long)N_ * D_,
                                       nullptr, part);

  // 8) final: gate(row)*(obuf@Wo) + bo -> d_out
  wsplitT<<<gT, blk, 0, stream>>>(Wo, Whi, Wlo);
  mfgemm<2><<<gProj, blk, 0, stream>>>(obuf, Whi, Wlo, bo, out, nullptr, nullptr,
                                       BN_, D_, D_, 0, 0, part, nullptr);
}

// Round 5
// 572.400 us; speedup vs baseline: 3.3711x; 2.1964x over previous
//
#include <hip/hip_runtime.h>
#include <cmath>

// Problem constants (fixed by the reference file)
#define B_   8
#define N_   512
#define D_   1024
#define H_   16
#define HD_  64
#define NI_  4
#define BN_  (B_*N_)      // 4096 rows when [B,N,*] is flattened
#define KVLEN (NI_*N_)    // 2048 keys per attention group

typedef __attribute__((ext_vector_type(8)))  short  bf16x8;   // 8 bf16 bit patterns
typedef __attribute__((ext_vector_type(8)))  __bf16 bf16x8_t; // builtin operand type
typedef __attribute__((ext_vector_type(16))) float  f32x16;
typedef __attribute__((ext_vector_type(4)))  short  s16x4;

// round-to-nearest-even bf16 conversion (bit trick)
__device__ __forceinline__ short bf16_rn(float x) {
  unsigned u = __float_as_uint(x);
  unsigned r = (u + 0x7FFFu + ((u >> 16) & 1u)) >> 16;
  return (short)r;
}

// RN hi/lo split: x = hi + lo + eps, |eps| <~ 2^-18 |x|.
__device__ __forceinline__ void split2(float x, short& hi, short& lo) {
  hi = bf16_rn(x);
  float h = __uint_as_float(((unsigned)(unsigned short)hi) << 16);
  float r = x - h;              // exact (Dekker-style split)
  lo = bf16_rn(r);
}

__device__ __forceinline__ f32x16 mfma_bf16(bf16x8 a, bf16x8 b, f32x16 c) {
  return __builtin_amdgcn_mfma_f32_32x32x16_bf16(
      __builtin_bit_cast(bf16x8_t, a), __builtin_bit_cast(bf16x8_t, b), c, 0, 0, 0);
}

// =====================================================================
// Weight transpose + hi/lo split: W[K=1024][C=1024] fp32 ->
// Thi/Tlo[C][K] bf16.  64x64 tiles via LDS.
// =====================================================================
__global__ __launch_bounds__(256) void wsplitT(const float* __restrict__ W,
                                               short* __restrict__ Thi,
                                               short* __restrict__ Tlo)
{
  __shared__ float tile[64][65];
  const int t  = threadIdx.x;
  const int kb = blockIdx.y * 64;   // source row block (k)
  const int cb = blockIdx.x * 64;   // source col block
  const int r0 = t >> 4;            // 0..15
  const int c4 = t & 15;            // float4 index within row
  #pragma unroll
  for (int i = 0; i < 4; i++) {
    const int r = r0 + i * 16;
    *(float4*)&tile[r][c4 * 4] = *(const float4*)&W[(long)(kb + r) * D_ + cb + c4 * 4];
  }
  __syncthreads();
  #pragma unroll
  for (int i = 0; i < 4; i++) {
    const int c = r0 + i * 16;      // source col = output row
    short hi[4], lo[4];
    #pragma unroll
    for (int e = 0; e < 4; e++)
      split2(tile[c4 * 4 + e][c], hi[e], lo[e]);
    *(s16x4*)&Thi[(long)(cb + c) * D_ + kb + c4 * 4] = *(s16x4*)hi;
    *(s16x4*)&Tlo[(long)(cb + c) * D_ + kb + c4 * 4] = *(s16x4*)lo;
  }
}

// =====================================================================
// Split-bf16 MFMA GEMM.  BM=BN=128, BK=32, 256 threads = 4 waves (2x2),
// per-wave 64x64 output as 2x2 frags of v_mfma_f32_32x32x16_bf16.
// MODE 0: C = A@B + bias (fp32 out)
// MODE 1: split output: Chi/Clo bf16 = A@B + bias  (for ik)
// MODE 2: C = gate(row)*(A@B) + bias, gate = 1 + sum8(part_in[row])/512
// MODE 3: part_out[(bz*N_+row)*8 + bx*2 + wc] = per-wave 64-col partial
//         row sum of sigmoid(acc*SCALE/H). (one slot per wave: no races)
// =====================================================================
#define BM 128
#define BN 128
#define BK 32
#define PAD 40   // LDS row stride in shorts (bank-spread padding)

template<int MODE>
__global__ __launch_bounds__(256) void mfgemm(
    const float* __restrict__ A, const short* __restrict__ Bhi,
    const short* __restrict__ Blo, const float* __restrict__ bias,
    float* __restrict__ C, short* __restrict__ Chi, short* __restrict__ Clo,
    int M, int Nc, int K, long sA, long sB,
    const float* __restrict__ part_in, float* __restrict__ part_out)
{
  __shared__ short As[2][BM][PAD];   // [hi/lo][row][k]
  __shared__ short Bs[2][BN][PAD];   // [hi/lo][col][k]
  const int t  = threadIdx.x;
  const int bx = blockIdx.x, by = blockIdx.y, bz = blockIdx.z;
  A   += (long)bz * sA;
  Bhi += (long)bz * sB;
  Blo += (long)bz * sB;
  const int rowBase = by * BM, colBase = bx * BN;

  const int sa_row = t >> 3;        // + 32*i
  const int sa_c4  = t & 7;
  const int sb_col = t >> 2;        // + 64*(i&1)
  const int sb_q   = t & 3;

  float4 aReg[4];
  int4   bReg[4];

  auto loadTile = [&](int k0) {
    #pragma unroll
    for (int i = 0; i < 4; i++)
      aReg[i] = *(const float4*)&A[(long)(rowBase + sa_row + 32 * i) * K + k0 + sa_c4 * 4];
    #pragma unroll
    for (int i = 0; i < 4; i++) {
      const short* p = (i >> 1) ? Blo : Bhi;
      bReg[i] = *(const int4*)&p[(long)(colBase + (i & 1) * 64 + sb_col) * K + k0 + sb_q * 8];
    }
  };
  auto writeTile = [&]() {
    #pragma unroll
    for (int i = 0; i < 4; i++) {
      short hi[4], lo[4];
      split2(aReg[i].x, hi[0], lo[0]);
      split2(aReg[i].y, hi[1], lo[1]);
      split2(aReg[i].z, hi[2], lo[2]);
      split2(aReg[i].w, hi[3], lo[3]);
      *(s16x4*)&As[0][sa_row + 32 * i][sa_c4 * 4] = *(s16x4*)hi;
      *(s16x4*)&As[1][sa_row + 32 * i][sa_c4 * 4] = *(s16x4*)lo;
    }
    #pragma unroll
    for (int i = 0; i < 4; i++)
      *(int4*)&Bs[i >> 1][(i & 1) * 64 + sb_col][sb_q * 8] = bReg[i];
  };

  const int w = t >> 6, lane = t & 63;
  const int wr = w >> 1, wc = w & 1;
  const int lrow = lane & 31, lk = lane >> 5;

  f32x16 acc[2][2] = {};

  auto compute = [&]() {
    #pragma unroll
    for (int kh = 0; kh < 2; kh++) {
      const int ko = kh * 16 + lk * 8;
      bf16x8 ah[2], al[2], bh[2], bl[2];
      #pragma unroll
      for (int m = 0; m < 2; m++) {
        ah[m] = *(const bf16x8*)&As[0][wr * 64 + m * 32 + lrow][ko];
        al[m] = *(const bf16x8*)&As[1][wr * 64 + m * 32 + lrow][ko];
      }
      #pragma unroll
      for (int n = 0; n < 2; n++) {
        bh[n] = *(const bf16x8*)&Bs[0][wc * 64 + n * 32 + lrow][ko];
        bl[n] = *(const bf16x8*)&Bs[1][wc * 64 + n * 32 + lrow][ko];
      }
      #pragma unroll
      for (int m = 0; m < 2; m++)
        #pragma unroll
        for (int n = 0; n < 2; n++) {
          acc[m][n] = mfma_bf16(al[m], bh[n], acc[m][n]);
          acc[m][n] = mfma_bf16(ah[m], bl[n], acc[m][n]);
          acc[m][n] = mfma_bf16(ah[m], bh[n], acc[m][n]);
        }
    }
  };

  const int NT = K / BK;
  loadTile(0);
  writeTile();
  __syncthreads();
  for (int tt = 0; tt < NT; ++tt) {
    if (tt + 1 < NT) loadTile((tt + 1) * BK);
    compute();
    __syncthreads();
    if (tt + 1 < NT) { writeTile(); __syncthreads(); }
  }

  // ---------------- epilogue ----------------
  if (MODE == 3) {
    const float sc = 0.125f / 16.f;   // SCALE/H
    #pragma unroll
    for (int m = 0; m < 2; m++)
      #pragma unroll
      for (int r = 0; r < 16; r++) {
        const int row = rowBase + wr * 64 + m * 32 + (r & 3) + 8 * (r >> 2) + 4 * lk;
        float v = 1.f / (1.f + __expf(-acc[m][0][r] * sc))
                + 1.f / (1.f + __expf(-acc[m][1][r] * sc));
        v += __shfl_xor(v, 1);  v += __shfl_xor(v, 2);  v += __shfl_xor(v, 4);
        v += __shfl_xor(v, 8);  v += __shfl_xor(v, 16);
        if (lrow == 0)
          part_out[(long)(bz * N_ + row) * 8 + bx * 2 + wc] = v;
      }
    return;
  }

  float bcol[2];
  #pragma unroll
  for (int n = 0; n < 2; n++)
    bcol[n] = bias[colBase + wc * 64 + n * 32 + lrow];

  #pragma unroll
  for (int m = 0; m < 2; m++) {
    #pragma unroll
    for (int r = 0; r < 16; r++) {
      const int row = rowBase + wr * 64 + m * 32 + (r & 3) + 8 * (r >> 2) + 4 * lk;
      float g = 1.f;
      if (MODE == 2) {
        const float4 p0 = *(const float4*)&part_in[(long)row * 8];
        const float4 p1 = *(const float4*)&part_in[(long)row * 8 + 4];
        g = 1.f + (p0.x + p0.y + p0.z + p0.w + p1.x + p1.y + p1.z + p1.w)
                  * (1.f / 512.f);
      }
      #pragma unroll
      for (int n = 0; n < 2; n++) {
        const int col = colBase + wc * 64 + n * 32 + lrow;
        const float val = acc[m][n][r] * g + bcol[n];
        if (MODE == 1) {
          short hi, lo;
          split2(val, hi, lo);
          Chi[(long)row * Nc + col] = hi;
          Clo[(long)row * Nc + col] = lo;
        } else {
          C[(long)row * Nc + col] = val;
        }
      }
    }
  }
}

// =====================================================================
// MFMA grouped flash attention, bf16 compute, fp32 softmax state.
// grid (N/128, H, B), 256 thr = 4 waves; wave owns 32 q rows.
// - Swapped QK^T: scores = mfma(A=K, B=Q) -> C[col=q (lane&31)][row=kv].
// - STATIC softmax max: RMS-normed q,k => |s*SCALE| <= 8 (Cauchy-Schwarz),
//   so p = exp(s*0.125 - 8): no online max, no rescale passes.
// - PV A-frag built in-register: pack p pairs to bf16, 8x shfl_xor(32) to
//   swap kv halves between lane halves, cndmask-select per half.
// - QK-RMSNorm folded into staging (Q: lane + shfl32; K: 8-lane shfl tree).
// - K LDS: 128B rows, XOR-swizzled 16B chunks (^(kv&7)<<4 bytes).
// - V LDS: transposed [d][kv], 80B rows -> bank-rotated, conflict-free.
// =====================================================================
__global__ __launch_bounds__(256) void attn_mfma(
    const float* __restrict__ q, const float* __restrict__ k,
    const float* __restrict__ v, const float* __restrict__ qnw,
    const float* __restrict__ knw, float* __restrict__ out)
{
  const int b  = blockIdx.z, h = blockIdx.y, qb = blockIdx.x;
  const int g  = b >> 2;
  const int t  = threadIdx.x;
  const int w  = t >> 6;
  const int lane = t & 63;
  const int l31 = lane & 31, hi = lane >> 5;

  __shared__ short Ks[32 * 64];   // [kv][hd] bf16, swizzled
  __shared__ short Vs[64 * 40];   // [d][kv] bf16, stride 40 shorts (80B)

  // ---- Q: load + RMSNorm + B-operand frags (q = col = lane&31) ----
  const int qrow = qb * 128 + w * 32 + l31;
  const float* qp = q + ((long)b * N_ + qrow) * D_ + h * HD_ + hi * 8;
  float qv[4][8];
  float ss = 0.f;
  #pragma unroll
  for (int c = 0; c < 4; c++) {
    *(float4*)&qv[c][0] = *(const float4*)&qp[c * 16];
    *(float4*)&qv[c][4] = *(const float4*)&qp[c * 16 + 4];
    #pragma unroll
    for (int j = 0; j < 8; j++) ss += qv[c][j] * qv[c][j];
  }
  ss += __shfl_xor(ss, 32);                   // partner holds other hd half
  const float qr = rsqrtf(ss * (1.f / 64.f) + 1e-6f);
  bf16x8 qf[4];
  #pragma unroll
  for (int c = 0; c < 4; c++)
    #pragma unroll
    for (int j = 0; j < 8; j++)
      qf[c][j] = bf16_rn(qv[c][j] * qr * qnw[c * 16 + hi * 8 + j]);

  // staging maps
  const int skv = t >> 3, sg = t & 7;   // K: row skv (32), chunk sg (8 floats)
  const int vkv = t & 31, vg = t >> 5;  // V: row vkv (32), chunk vg (8 floats)

  f32x16 oacc[2] = {};
  float l = 0.f;

  for (int kt = 0; kt < KVLEN / 32; ++kt) {
    const int inst = (kt * 32) >> 9;
    const int nn0  = (kt * 32) & (N_ - 1);
    const long rowK = ((long)(g * NI_ + inst) * N_ + nn0 + skv) * D_ + h * HD_ + sg * 8;
    const long rowV = ((long)(g * NI_ + inst) * N_ + nn0 + vkv) * D_ + h * HD_ + vg * 8;
    float kf32[8], vf32[8];
    *(float4*)&kf32[0] = *(const float4*)&k[rowK];
    *(float4*)&kf32[4] = *(const float4*)&k[rowK + 4];
    *(float4*)&vf32[0] = *(const float4*)&v[rowV];
    *(float4*)&vf32[4] = *(const float4*)&v[rowV + 4];
    // K RMS across the 8 lanes sharing row skv (lanes differ in bits 0-2)
    float ks2 = 0.f;
    #pragma unroll
    for (int j = 0; j < 8; j++) ks2 += kf32[j] * kf32[j];
    ks2 += __shfl_xor(ks2, 1);
    ks2 += __shfl_xor(ks2, 2);
    ks2 += __shfl_xor(ks2, 4);
    const float kr = rsqrtf(ks2 * (1.f / 64.f) + 1e-6f);

    __syncthreads();   // previous tile fully consumed
    bf16x8 kb;
    #pragma unroll
    for (int j = 0; j < 8; j++) kb[j] = bf16_rn(kf32[j] * kr * knw[sg * 8 + j]);
    *(bf16x8*)&Ks[skv * 64 + ((sg * 8) ^ ((skv & 7) << 3))] = kb;
    #pragma unroll
    for (int e = 0; e < 8; e++)
      Vs[(vg * 8 + e) * 40 + vkv] = bf16_rn(vf32[e]);
    __syncthreads();

    // ---- QK^T: scores[kv][q], C: col=lane&31=q, row=crow(r,hi)=kv ----
    f32x16 sc = {};
    #pragma unroll
    for (int c = 0; c < 4; c++) {
      bf16x8 kfr = *(const bf16x8*)&Ks[l31 * 64 + (((2 * c + hi) * 8) ^ ((l31 & 7) << 3))];
      sc = mfma_bf16(kfr, qf[c], sc);
    }
    // ---- softmax with static max 8 ----
    float p[16];
    #pragma unroll
    for (int r = 0; r < 16; r++) { p[r] = __expf(sc[r] * 0.125f - 8.f); l += p[r]; }
    // ---- build PV A-frags: lane needs p[kv=16ks+8hi+j][q=lane&31] ----
    unsigned wd[8], sw[8];
    #pragma unroll
    for (int i = 0; i < 8; i++)
      wd[i] = ((unsigned)(unsigned short)bf16_rn(p[2 * i + 1]) << 16)
            | (unsigned short)bf16_rn(p[2 * i]);
    #pragma unroll
    for (int i = 0; i < 8; i++) sw[i] = __shfl_xor(wd[i], 32);
    int4 f0 = { (int)(hi ? sw[2] : wd[0]), (int)(hi ? sw[3] : wd[1]),
                (int)(hi ? wd[2] : sw[0]), (int)(hi ? wd[3] : sw[1]) };
    int4 f1 = { (int)(hi ? sw[6] : wd[4]), (int)(hi ? sw[7] : wd[5]),
                (int)(hi ? wd[6] : sw[4]), (int)(hi ? wd[7] : sw[5]) };
    // ---- PV: out[q][d] += P * V ----
    #pragma unroll
    for (int n = 0; n < 2; n++) {
      bf16x8 v0 = *(const bf16x8*)&Vs[(n * 32 + l31) * 40 + hi * 8];
      bf16x8 v1 = *(const bf16x8*)&Vs[(n * 32 + l31) * 40 + 16 + hi * 8];
      oacc[n] = mfma_bf16(__builtin_bit_cast(bf16x8, f0), v0, oacc[n]);
      oacc[n] = mfma_bf16(__builtin_bit_cast(bf16x8, f1), v1, oacc[n]);
    }
  }

  // ---- epilogue: divide by l (per q row) and store ----
  l += __shfl_xor(l, 32);                 // both halves now have full l(q)
  const float linv = 1.f / l;
  float lr[16];
  #pragma unroll
  for (int r = 0; r < 16; r++)
    lr[r] = __shfl(linv, (r & 3) + 8 * (r >> 2) + 4 * hi);
  #pragma unroll
  for (int r = 0; r < 16; r++) {
    const int qg = qb * 128 + w * 32 + (r & 3) + 8 * (r >> 2) + 4 * hi;
    float* op = out + ((long)b * N_ + qg) * D_ + h * HD_ + l31;
    op[0]  = oacc[0][r] * lr[r];
    op[32] = oacc[1][r] * lr[r];
  }
}

// =====================================================================
// inst_feat[b,n,:] = instance_mask[b,n,0..3] @ instance_embed[0,0..3,:]
// =====================================================================
__global__ __launch_bounds__(256) void instfeat(
    const float* __restrict__ mask, const float* __restrict__ emb,
    float* __restrict__ outf)
{
  const long idx = (long)blockIdx.x * 256 + threadIdx.x;
  const int  d4  = (int)(idx & (D_ / 4 - 1));
  const long bn  = idx >> 8;
  const float* mk = mask + bn * NI_;
  float4 acc = {0.f, 0.f, 0.f, 0.f};
  #pragma unroll
  for (int i = 0; i < NI_; i++) {
    const float mm = mk[i];
    const float4 e = *(const float4*)&emb[(long)i * D_ + d4 * 4];
    acc.x = fmaf(mm, e.x, acc.x);
    acc.y = fmaf(mm, e.y, acc.y);
    acc.z = fmaf(mm, e.z, acc.z);
    acc.w = fmaf(mm, e.w, acc.w);
  }
  *(float4*)&outf[bn * D_ + d4 * 4] = acc;
}

// =====================================================================
extern "C" void kernel_launch(void* const* d_in, const int* in_sizes, int n_in,
                              void* d_out, int out_size, void* d_ws, size_t ws_size,
                              hipStream_t stream)
{
  const float* x    = (const float*)d_in[0];
  const float* mask = (const float*)d_in[1];
  const float* Wq   = (const float*)d_in[2];
  const float* bq   = (const float*)d_in[3];
  const float* Wk   = (const float*)d_in[4];
  const float* bk   = (const float*)d_in[5];
  const float* Wv   = (const float*)d_in[6];
  const float* bv   = (const float*)d_in[7];
  const float* Wo   = (const float*)d_in[8];
  const float* bo   = (const float*)d_in[9];
  const float* Wiq  = (const float*)d_in[10];
  const float* biq  = (const float*)d_in[11];
  const float* Wik  = (const float*)d_in[12];
  const float* bik  = (const float*)d_in[13];
  const float* emb  = (const float*)d_in[14];
  const float* qnw  = (const float*)d_in[15];
  const float* knw  = (const float*)d_in[16];
  float* out = (float*)d_out;

  float* ws   = (float*)d_ws;
  const size_t SZ = (size_t)BN_ * D_;
  float* qbuf = ws;
  float* kbuf = qbuf + SZ;
  float* vbuf = kbuf + SZ;
  float* obuf = vbuf + SZ;
  float* part = obuf + SZ;              // [B*N, 8] per-wave gate partials
  short* Whi  = (short*)(part + (size_t)BN_ * 8);
  short* Wlo  = Whi + (size_t)D_ * D_;
  float* iq    = qbuf;                  // aliases (post-attention)
  float* ifeat = kbuf;
  short* ikh   = (short*)vbuf;
  short* ikl   = ikh + SZ;

  const dim3 blk(256);
  const dim3 gT(D_ / 64, D_ / 64, 1);           // weight transpose grid
  const dim3 gProj(D_ / BN, BN_ / BM, 1);       // 8 x 32
  const dim3 gGate(N_ / BN, N_ / BM, B_);       // 4 x 4 x 8
  const dim3 gAttn(N_ / 128, H_, B_);           // 4 x 16 x 8

  // 1) QKV projections (raw, un-normed; RMSNorm folds into attention)
  wsplitT<<<gT, blk, 0, stream>>>(Wq, Whi, Wlo);
  mfgemm<0><<<gProj, blk, 0, stream>>>(x, Whi, Wlo, bq, qbuf, nullptr, nullptr,
                                       BN_, D_, D_, 0, 0, nullptr, nullptr);
  wsplitT<<<gT, blk, 0, stream>>>(Wk, Whi, Wlo);
  mfgemm<0><<<gProj, blk, 0, stream>>>(x, Whi, Wlo, bk, kbuf, nullptr, nullptr,
                                       BN_, D_, D_, 0, 0, nullptr, nullptr);
  wsplitT<<<gT, blk, 0, stream>>>(Wv, Whi, Wlo);
  mfgemm<0><<<gProj, blk, 0, stream>>>(x, Whi, Wlo, bv, vbuf, nullptr, nullptr,
                                       BN_, D_, D_, 0, 0, nullptr, nullptr);

  // 2) MFMA grouped flash attention (with fused QK-RMSNorm) -> obuf
  attn_mfma<<<gAttn, blk, 0, stream>>>(qbuf, kbuf, vbuf, qnw, knw, obuf);

  // 3) IQ = obuf@Wiq+biq (overwrites qbuf)
  wsplitT<<<gT, blk, 0, stream>>>(Wiq, Whi, Wlo);
  mfgemm<0><<<gProj, blk, 0, stream>>>(obuf, Whi, Wlo, biq, iq, nullptr, nullptr,
                                       BN_, D_, D_, 0, 0, nullptr, nullptr);

  // 4) inst_feat (overwrites kbuf)
  instfeat<<<(BN_ * D_ / 4) / 256, blk, 0, stream>>>(mask, emb, ifeat);

  // 5) IK = inst_feat@Wik+bik, emitted as split bf16 (overwrites vbuf)
  wsplitT<<<gT, blk, 0, stream>>>(Wik, Whi, Wlo);
  mfgemm<1><<<gProj, blk, 0, stream>>>(ifeat, Whi, Wlo, bik, nullptr, ikh, ikl,
                                       BN_, D_, D_, 0, 0, nullptr, nullptr);

  // 6) gate partials: per-batch IQ[b] @ IK[b]^T, sigmoid, per-wave partials
  mfgemm<3><<<gGate, blk, 0, stream>>>(iq, ikh, ikl, nullptr, nullptr, nullptr, nullptr,
                                       N_, N_, D_, (long)N_ * D_, (long)N_ * D_,
                                       nullptr, part);

  // 7) final: gate(row)*(obuf@Wo) + bo -> d_out
  wsplitT<<<gT, blk, 0, stream>>>(Wo, Whi, Wlo);
  mfgemm<2><<<gProj, blk, 0, stream>>>(obuf, Whi, Wlo, bo, out, nullptr, nullptr,
                                       BN_, D_, D_, 0, 0, part, nullptr);
}